// Round 1
// baseline (508.827 us; speedup 1.0000x reference)
//
#include <hip/hip_runtime.h>
#include <math.h>

// Problem-instance constants (B=2, C=3, H=W=128, out_size=256)
#define B_    2
#define C_    3
#define N_    16384    // H*W
#define OS_   256
#define OUT_  65536    // OS*OS
#define NC_   4        // c-values per thread (amortizes LDS reads over 4 exp/dot chains)
#define SC_   512      // n-values staged into LDS per chunk (512*12*4B = 24 KiB)
#define LOG2E 1.44269504088896340736f

// ---------------------------------------------------------------------------
// Prep: pack per-(b,n): [k2*nx, k2*ny, k2*nz, v0w, v1w, v2w, v0^2 w, v1^2 w, v2^2 w, 0,0,0]
// Stride 12 floats (48B) keeps every record 16B-aligned for float4/ds_read_b128.
// ---------------------------------------------------------------------------
__global__ __launch_bounds__(256) void prep_kernel(
    const float* __restrict__ img, const float* __restrict__ nm,
    const int* __restrict__ mask, const int* __restrict__ kappa,
    float* __restrict__ pk)
{
    int idx = blockIdx.x * 256 + threadIdx.x;
    if (idx >= B_ * N_) return;
    int b = idx / N_;
    int n = idx - b * N_;
    float k2 = (float)kappa[0] * LOG2E;
    float w  = (mask[idx] > 0) ? 1.0f : 0.0f;
    const float* nb = nm  + (size_t)b * 3  * N_ + n;
    const float* ib = img + (size_t)b * C_ * N_ + n;
    float nx = nb[0], ny = nb[N_], nz = nb[2 * N_];
    float v0 = ib[0], v1 = ib[N_], v2 = ib[2 * N_];
    float* o = pk + (size_t)idx * 12;
    o[0] = k2 * nx;   o[1] = k2 * ny;   o[2] = k2 * nz;
    o[3] = v0 * w;    o[4] = v1 * w;    o[5] = v2 * w;
    o[6] = v0 * v0 * w; o[7] = v1 * v1 * w; o[8] = v2 * v2 * w;
    o[9] = 0.0f; o[10] = 0.0f; o[11] = 0.0f;
}

// ---------------------------------------------------------------------------
// Main: each block = 256 threads handles one (b, 1024-wide c-tile, n-split).
// Each thread owns NC_=4 directions; inner loop over staged n-chunk does
// 3 broadcast ds_read_b128 + per-c {3 FMA dot, 1 v_exp_f32, 6 FMA accumulate}.
// Partials (pre-coef) written to ws for the finalize pass.
// ---------------------------------------------------------------------------
__global__ __launch_bounds__(256) void main_kernel(
    const float* __restrict__ pk, const int* __restrict__ kappa,
    float* __restrict__ part, int nsplit)
{
    __shared__ float4 lds4[SC_ * 3];

    const int ctiles = OUT_ / (256 * NC_);   // 64 c-tiles per b
    int bpb   = ctiles * nsplit;             // blocks per b
    int b     = blockIdx.x / bpb;
    int r     = blockIdx.x - b * bpb;
    int ctile = r / nsplit;
    int split = r - ctile * nsplit;
    int tid   = threadIdx.x;

    float k2 = (float)kappa[0] * LOG2E;

    // Stereographic direction M for this thread's 4 c's (v = c>>8, u = c&255)
    int c0 = ctile * (256 * NC_) + tid * NC_;
    float Mx[NC_], My[NC_], Mz[NC_];
#pragma unroll
    for (int j = 0; j < NC_; j++) {
        int c = c0 + j;
        int u = c & (OS_ - 1);
        int v = c >> 8;
        float p = 4.0f * ((u + 0.5f) / OS_ - 0.5f);
        float q = -4.0f * ((v + 0.5f) / OS_ - 0.5f);
        float pp = p * p + q * q;
        float inv = 1.0f / (1.0f + pp);
        Mx[j] = 2.0f * p * inv;
        My[j] = 2.0f * q * inv;
        Mz[j] = (1.0f - pp) * inv;
    }

    float acc[NC_][6];
#pragma unroll
    for (int j = 0; j < NC_; j++)
#pragma unroll
        for (int i = 0; i < 6; i++) acc[j][i] = 0.0f;

    int nchunk = N_ / nsplit;
    int nb0    = split * nchunk;

    for (int sub = 0; sub < nchunk; sub += SC_) {
        const float4* src = (const float4*)(pk + ((size_t)b * N_ + nb0 + sub) * 12);
#pragma unroll
        for (int t = 0; t < (SC_ * 3) / 256; t++)      // 6 float4 per thread, coalesced
            lds4[t * 256 + tid] = src[t * 256 + tid];
        __syncthreads();

        for (int i = 0; i < SC_; i++) {
            float4 a0 = lds4[i * 3 + 0];   // k2*nx, k2*ny, k2*nz, v0w
            float4 a1 = lds4[i * 3 + 1];   // v1w, v2w, v0^2w, v1^2w
            float4 a2 = lds4[i * 3 + 2];   // v2^2w, pad...
#pragma unroll
            for (int j = 0; j < NC_; j++) {
                float arg = fmaf(a0.x, Mx[j], fmaf(a0.y, My[j], fmaf(a0.z, Mz[j], -k2)));
                float f = __builtin_amdgcn_exp2f(arg);   // = exp(-k*(1-dp))
                acc[j][0] = fmaf(f, a0.w, acc[j][0]);
                acc[j][1] = fmaf(f, a1.x, acc[j][1]);
                acc[j][2] = fmaf(f, a1.y, acc[j][2]);
                acc[j][3] = fmaf(f, a1.z, acc[j][3]);
                acc[j][4] = fmaf(f, a1.w, acc[j][4]);
                acc[j][5] = fmaf(f, a2.x, acc[j][5]);
            }
        }
        __syncthreads();
    }

    // part[((b*OUT + c)*nsplit + split)*6 + i]
#pragma unroll
    for (int j = 0; j < NC_; j++) {
        size_t base = (((size_t)b * OUT_ + (c0 + j)) * (size_t)nsplit + split) * 6;
#pragma unroll
        for (int i = 0; i < 6; i++) part[base + i] = acc[j][i];
    }
}

// ---------------------------------------------------------------------------
// Finalize: reduce partials across splits, apply coef, out = num/(s+0.001),
// write in (B, C, OS, OS) layout.
// ---------------------------------------------------------------------------
__global__ __launch_bounds__(256) void finalize_kernel(
    const float* __restrict__ part, const int* __restrict__ kappa,
    float* __restrict__ out, int nsplit)
{
    int idx = blockIdx.x * 256 + threadIdx.x;
    if (idx >= B_ * OUT_) return;
    int b = idx / OUT_;
    int c = idx - b * OUT_;

    float k = (float)kappa[0];
    float coef = k / (2.0f * 3.14159265358979323846f * (1.0f - expf(-2.0f * k)));

    float s[6] = {0, 0, 0, 0, 0, 0};
    const float* pbase = part + (size_t)idx * (size_t)nsplit * 6;
    for (int sp = 0; sp < nsplit; sp++) {
#pragma unroll
        for (int i = 0; i < 6; i++) s[i] += pbase[sp * 6 + i];
    }
#pragma unroll
    for (int ch = 0; ch < C_; ch++) {
        out[((size_t)(b * C_ + ch)) * OUT_ + c] = (coef * s[3 + ch]) / (coef * s[ch] + 0.001f);
    }
}

// ---------------------------------------------------------------------------
extern "C" void kernel_launch(void* const* d_in, const int* in_sizes, int n_in,
                              void* d_out, int out_size, void* d_ws, size_t ws_size,
                              hipStream_t stream)
{
    const float* img   = (const float*)d_in[0];
    const float* nm    = (const float*)d_in[1];
    const int*   mask  = (const int*)d_in[2];
    const int*   kappa = (const int*)d_in[3];
    // d_in[4] = out_size scalar (hard-coded as OS_)
    float* out = (float*)d_out;

    char*  ws       = (char*)d_ws;
    size_t pk_bytes = (size_t)B_ * N_ * 12 * sizeof(float);
    float* pk       = (float*)ws;
    float* part     = (float*)(ws + pk_bytes);

    // Choose n-split by available workspace (deterministic: ws_size is fixed)
    int nsplit = 8;
    while (nsplit > 1 &&
           pk_bytes + (size_t)B_ * OUT_ * (size_t)nsplit * 6 * sizeof(float) > ws_size)
        nsplit >>= 1;

    hipLaunchKernelGGL(prep_kernel, dim3((B_ * N_ + 255) / 256), dim3(256), 0, stream,
                       img, nm, mask, kappa, pk);

    int blocks = B_ * (OUT_ / (256 * NC_)) * nsplit;
    hipLaunchKernelGGL(main_kernel, dim3(blocks), dim3(256), 0, stream,
                       pk, kappa, part, nsplit);

    hipLaunchKernelGGL(finalize_kernel, dim3((B_ * OUT_ + 255) / 256), dim3(256), 0, stream,
                       part, kappa, out, nsplit);
}

// Round 2
// 155.947 us; speedup vs baseline: 3.2628x; 3.2628x over previous
//
#include <hip/hip_runtime.h>
#include <math.h>

// Problem-instance constants (B=2, C=3, H=W=128, out_size=256, kappa=100)
#define B_    2
#define C_    3
#define N_    16384    // H*W
#define OS_   256
#define OUT_  65536    // OS*OS
#define NZ_   16       // z-bands
#define NF_   32       // azimuth sectors
#define NB_   512      // NZ_*NF_ spherical bins
#define TAU_  30.0f    // skip bins where k*(1-dp) > TAU for the whole (tile,cell)
#define LOG2E 1.44269504088896340736f
#define PI_   3.14159265358979323846f

// ---------------------------------------------------------------------------
__device__ __forceinline__ int pixel_bin(float nx, float ny, float nz) {
    int zi = (int)((nz + 1.0f) * (NZ_ * 0.5f));
    zi = min(max(zi, 0), NZ_ - 1);
    float phi = atan2f(ny, nx);                       // [-pi, pi]
    int fi = (int)((phi + PI_) * (NF_ / (2.0f * PI_)));
    fi = min(max(fi, 0), NF_ - 1);
    return zi * NF_ + fi;
}

__global__ __launch_bounds__(256) void zero_kernel(int* __restrict__ p, int n) {
    int i = blockIdx.x * 256 + threadIdx.x;
    if (i < n) p[i] = 0;
}

// Histogram of masked-in pixels over bins
__global__ __launch_bounds__(256) void hist_kernel(
    const float* __restrict__ nm, const int* __restrict__ mask, int* __restrict__ cnt)
{
    int idx = blockIdx.x * 256 + threadIdx.x;
    if (idx >= B_ * N_) return;
    if (mask[idx] <= 0) return;
    int b = idx / N_, n = idx - b * N_;
    const float* nb = nm + (size_t)b * 3 * N_ + n;
    int bin = pixel_bin(nb[0], nb[N_], nb[2 * N_]);
    atomicAdd(&cnt[b * NB_ + bin], 1);
}

// Exclusive scan over 512 bins per b (serial per b — trivial size)
__global__ void scan_kernel(const int* __restrict__ cnt,
                            int* __restrict__ binStart, int* __restrict__ off)
{
    int b = threadIdx.x;
    if (b >= B_) return;
    int acc = 0;
    for (int i = 0; i < NB_; i++) {
        binStart[b * (NB_ + 1) + i] = acc;
        off[b * NB_ + i] = acc;
        acc += cnt[b * NB_ + i];
    }
    binStart[b * (NB_ + 1) + NB_] = acc;
}

// Scatter masked-in pixel records into bin-sorted order.
// Record: [k2*nx, k2*ny, k2*nz, v0, v1, v2, v0^2, v1^2, v2^2, 0,0,0] (48B)
__global__ __launch_bounds__(256) void scatter_kernel(
    const float* __restrict__ img, const float* __restrict__ nm,
    const int* __restrict__ mask, const int* __restrict__ kappa,
    int* __restrict__ off, float* __restrict__ pk)
{
    int idx = blockIdx.x * 256 + threadIdx.x;
    if (idx >= B_ * N_) return;
    if (mask[idx] <= 0) return;
    int b = idx / N_, n = idx - b * N_;
    const float* nb = nm + (size_t)b * 3 * N_ + n;
    float nx = nb[0], ny = nb[N_], nz = nb[2 * N_];
    int bin = pixel_bin(nx, ny, nz);
    int pos = atomicAdd(&off[b * NB_ + bin], 1);
    const float* ib = img + (size_t)b * C_ * N_ + n;
    float v0 = ib[0], v1 = ib[N_], v2 = ib[2 * N_];
    float k2 = (float)kappa[0] * LOG2E;
    float* o = pk + ((size_t)b * N_ + pos) * 12;
    o[0] = k2 * nx; o[1] = k2 * ny; o[2] = k2 * nz;
    o[3] = v0;      o[4] = v1;      o[5] = v2;
    o[6] = v0 * v0; o[7] = v1 * v1; o[8] = v2 * v2;
    o[9] = 0.0f; o[10] = 0.0f; o[11] = 0.0f;
}

// ---------------------------------------------------------------------------
// Main: 1 wave per (b, 16x16 direction tile, bin-class s). Lane owns 4 c's.
// Exact cell-vs-tile-cone rejection; accepted bins processed densely with
// broadcast loads (all lanes read the same pixel record — L1/L2 resident).
// ---------------------------------------------------------------------------
__global__ __launch_bounds__(64) void main_kernel(
    const float* __restrict__ pk, const int* __restrict__ binStart,
    const int* __restrict__ kappa, float* __restrict__ part, int S)
{
    int bid  = blockIdx.x;
    int s    = bid % S;  bid /= S;
    int tile = bid & 255;
    int b    = bid >> 8;
    int tu   = tile & 15, tv = tile >> 4;
    int lane = threadIdx.x;

    float k  = (float)kappa[0];
    float k2 = k * LOG2E;

    // Directions for this lane's 4 c's within the 16x16 tile
    float Mx[4], My[4], Mz[4];
#pragma unroll
    for (int j = 0; j < 4; j++) {
        int cl = j * 64 + lane;
        int u  = tu * 16 + (cl & 15);
        int v  = tv * 16 + (cl >> 4);
        float p  = 4.0f * ((u + 0.5f) * (1.0f / OS_) - 0.5f);
        float q  = -4.0f * ((v + 0.5f) * (1.0f / OS_) - 0.5f);
        float pp = p * p + q * q;
        float inv = 1.0f / (1.0f + pp);
        Mx[j] = 2.0f * p * inv;
        My[j] = 2.0f * q * inv;
        Mz[j] = (1.0f - pp) * inv;
    }

    // Tile center direction + exact tile cone (min dot over the 256 M's)
    float pc  = 4.0f * ((tu * 16 + 8.0f) * (1.0f / OS_) - 0.5f);
    float qc  = -4.0f * ((tv * 16 + 8.0f) * (1.0f / OS_) - 0.5f);
    float ppc = pc * pc + qc * qc, invc = 1.0f / (1.0f + ppc);
    float Tx = 2.0f * pc * invc, Ty = 2.0f * qc * invc, Tz = (1.0f - ppc) * invc;

    float ctile = 1.0f;
#pragma unroll
    for (int j = 0; j < 4; j++)
        ctile = fminf(ctile, Mx[j] * Tx + My[j] * Ty + Mz[j] * Tz);
#pragma unroll
    for (int o = 32; o; o >>= 1) ctile = fminf(ctile, __shfl_xor(ctile, o));

    float dpthr = 1.0f - TAU_ / k;
    dpthr = fminf(fmaxf(dpthr, -1.0f), 1.0f);
    ctile = fminf(fmaxf(ctile, -1.0f), 1.0f);
    float theta = acosf(dpthr) + acosf(ctile);
    float rhs = (theta >= PI_) ? -2.0f : cosf(theta);   // accept all if cone covers sphere

    float rT   = sqrtf(Tx * Tx + Ty * Ty);
    float phiT = atan2f(Ty, Tx);

    float acc[4][6];
#pragma unroll
    for (int j = 0; j < 4; j++)
#pragma unroll
        for (int i = 0; i < 6; i++) acc[j][i] = 0.0f;

    const int* bs = binStart + b * (NB_ + 1);
    const float4* pkb = (const float4*)(pk + (size_t)b * N_ * 12);

    int ng = NB_ / (64 * S);          // S in {1,2,4,8}
    for (int g = 0; g < ng; g++) {
        // lane tests bin = s + S*(g*64+lane): exact max of n.T over the (z,phi) cell
        int bin = s + S * (g * 64 + lane);
        int zi = bin >> 5, fi = bin & 31;
        float z0 = -1.0f + zi * (2.0f / NZ_);
        float z1 = z0 + (2.0f / NZ_);
        float hw  = PI_ / NF_;
        float mid = -PI_ + (2.0f * PI_ / NF_) * fi + hw;
        float d = phiT - mid;
        d = d - (2.0f * PI_) * rintf(d * (0.5f / PI_));
        d = fabsf(d);
        float cmax = (d <= hw) ? 1.0f : cosf(d - hw);
        float A  = rT * cmax;
        float g0 = A * sqrtf(fmaxf(0.0f, 1.0f - z0 * z0)) + Tz * z0;
        float g1 = A * sqrtf(fmaxf(0.0f, 1.0f - z1 * z1)) + Tz * z1;
        float gm = fmaxf(g0, g1);
        if (A > 0.0f) {
            float s2 = A * A + Tz * Tz;
            float zs = Tz * rsqrtf(s2);
            if (zs > z0 && zs < z1) gm = sqrtf(s2);
        }
        unsigned long long mball = __ballot(gm >= rhs);

        while (mball) {
            int l = __builtin_ctzll(mball);
            mball &= mball - 1;
            int bb = s + S * (g * 64 + l);
            int st = bs[bb], en = bs[bb + 1];
            const float4* rec = pkb + (size_t)st * 3;
            for (int i = st; i < en; i++, rec += 3) {
                float4 a0 = rec[0];   // k2*nx, k2*ny, k2*nz, v0
                float4 a1 = rec[1];   // v1, v2, v0^2, v1^2
                float4 a2 = rec[2];   // v2^2, pad
#pragma unroll
                for (int j = 0; j < 4; j++) {
                    float arg = fmaf(a0.x, Mx[j], fmaf(a0.y, My[j], fmaf(a0.z, Mz[j], -k2)));
                    float f = __builtin_amdgcn_exp2f(arg);   // exp(-k*(1-dp))
                    acc[j][0] = fmaf(f, a0.w, acc[j][0]);
                    acc[j][1] = fmaf(f, a1.x, acc[j][1]);
                    acc[j][2] = fmaf(f, a1.y, acc[j][2]);
                    acc[j][3] = fmaf(f, a1.z, acc[j][3]);
                    acc[j][4] = fmaf(f, a1.w, acc[j][4]);
                    acc[j][5] = fmaf(f, a2.x, acc[j][5]);
                }
            }
        }
    }

    // part[((b*OUT + c)*S + s)*6 + i]
#pragma unroll
    for (int j = 0; j < 4; j++) {
        int cl = j * 64 + lane;
        int u  = tu * 16 + (cl & 15);
        int v  = tv * 16 + (cl >> 4);
        int c  = v * OS_ + u;
        size_t base = (((size_t)b * OUT_ + c) * S + s) * 6;
#pragma unroll
        for (int i = 0; i < 6; i++) part[base + i] = acc[j][i];
    }
}

// ---------------------------------------------------------------------------
__global__ __launch_bounds__(256) void finalize_kernel(
    const float* __restrict__ part, const int* __restrict__ kappa,
    float* __restrict__ out, int S)
{
    int idx = blockIdx.x * 256 + threadIdx.x;
    if (idx >= B_ * OUT_) return;
    int b = idx / OUT_;
    int c = idx - b * OUT_;

    float k = (float)kappa[0];
    float coef = k / (2.0f * PI_ * (1.0f - expf(-2.0f * k)));

    float s[6] = {0, 0, 0, 0, 0, 0};
    const float* pbase = part + (size_t)idx * (size_t)S * 6;
    for (int sp = 0; sp < S; sp++) {
#pragma unroll
        for (int i = 0; i < 6; i++) s[i] += pbase[sp * 6 + i];
    }
#pragma unroll
    for (int ch = 0; ch < C_; ch++) {
        out[((size_t)(b * C_ + ch)) * OUT_ + c] = (coef * s[3 + ch]) / (coef * s[ch] + 0.001f);
    }
}

// ---------------------------------------------------------------------------
extern "C" void kernel_launch(void* const* d_in, const int* in_sizes, int n_in,
                              void* d_out, int out_size, void* d_ws, size_t ws_size,
                              hipStream_t stream)
{
    const float* img   = (const float*)d_in[0];
    const float* nm    = (const float*)d_in[1];
    const int*   mask  = (const int*)d_in[2];
    const int*   kappa = (const int*)d_in[3];
    float* out = (float*)d_out;

    char*  ws       = (char*)d_ws;
    size_t pk_bytes = (size_t)B_ * N_ * 12 * sizeof(float);

    // Adaptive split count (deterministic: ws_size fixed per session)
    int S = 8;
    while (S > 1 &&
           pk_bytes + 64 * 1024 + (size_t)B_ * OUT_ * (size_t)S * 6 * sizeof(float) > ws_size)
        S >>= 1;

    float* pk        = (float*)ws;
    float* part      = (float*)(ws + pk_bytes);
    size_t part_b    = (size_t)B_ * OUT_ * (size_t)S * 6 * sizeof(float);
    int*   cnt       = (int*)(ws + pk_bytes + part_b);
    int*   off       = cnt + B_ * NB_;
    int*   binStart  = off + B_ * NB_;

    hipLaunchKernelGGL(zero_kernel, dim3((B_ * NB_ + 255) / 256), dim3(256), 0, stream,
                       cnt, B_ * NB_);
    hipLaunchKernelGGL(hist_kernel, dim3((B_ * N_ + 255) / 256), dim3(256), 0, stream,
                       nm, mask, cnt);
    hipLaunchKernelGGL(scan_kernel, dim3(1), dim3(64), 0, stream,
                       cnt, binStart, off);
    hipLaunchKernelGGL(scatter_kernel, dim3((B_ * N_ + 255) / 256), dim3(256), 0, stream,
                       img, nm, mask, kappa, off, pk);
    hipLaunchKernelGGL(main_kernel, dim3(B_ * 256 * S), dim3(64), 0, stream,
                       pk, binStart, kappa, part, S);
    hipLaunchKernelGGL(finalize_kernel, dim3((B_ * OUT_ + 255) / 256), dim3(256), 0, stream,
                       part, kappa, out, S);
}

// Round 3
// 128.304 us; speedup vs baseline: 3.9658x; 1.2154x over previous
//
#include <hip/hip_runtime.h>
#include <math.h>

// Problem-instance constants (B=2, C=3, H=W=128, out_size=256, kappa=100)
#define B_    2
#define C_    3
#define N_    16384    // H*W
#define OS_   256
#define OUT_  65536    // OS*OS
#define NZ_   32       // z-bands
#define NF_   64       // azimuth sectors
#define NB_   2048     // NZ_*NF_ spherical bins (equal solid angle)
#define S_    8        // bin-classes (wave-level split of bin space)
#define WPB_  2        // waves per block (record-stream split within an item)
#define TAU_  30.0f    // skip bins where k*(1-dp) > TAU for the whole (tile,cell)
#define LOG2E 1.44269504088896340736f
#define PI_   3.14159265358979323846f

// ---------------------------------------------------------------------------
__device__ __forceinline__ int pixel_bin(float nx, float ny, float nz) {
    int zi = (int)((nz + 1.0f) * (NZ_ * 0.5f));
    zi = min(max(zi, 0), NZ_ - 1);
    float phi = atan2f(ny, nx);                       // [-pi, pi]
    int fi = (int)((phi + PI_) * (NF_ / (2.0f * PI_)));
    fi = min(max(fi, 0), NF_ - 1);
    return zi * NF_ + fi;
}

// Histogram of masked-in pixels over bins
__global__ __launch_bounds__(256) void hist_kernel(
    const float* __restrict__ nm, const int* __restrict__ mask, int* __restrict__ cnt)
{
    int idx = blockIdx.x * 256 + threadIdx.x;
    if (idx >= B_ * N_) return;
    if (mask[idx] <= 0) return;
    int b = idx / N_, n = idx - b * N_;
    const float* nb = nm + (size_t)b * 3 * N_ + n;
    int bin = pixel_bin(nb[0], nb[N_], nb[2 * N_]);
    atomicAdd(&cnt[b * NB_ + bin], 1);
}

// Wave-parallel exclusive scan over NB_ bins; one 64-lane wave per b.
__global__ __launch_bounds__(64) void scan_kernel(
    const int* __restrict__ cnt, int* __restrict__ binStart, int* __restrict__ off)
{
    int b = blockIdx.x;
    int lane = threadIdx.x;
    const int per = NB_ / 64;          // 32 bins per lane
    int base = b * NB_ + lane * per;

    int sum = 0;
#pragma unroll
    for (int i = 0; i < per; i++) sum += cnt[base + i];

    int inc = sum;                      // inclusive scan across lanes
#pragma unroll
    for (int o = 1; o < 64; o <<= 1) {
        int t = __shfl_up(inc, o);
        if (lane >= o) inc += t;
    }
    int acc = inc - sum;                // exclusive prefix for this lane's chunk

#pragma unroll
    for (int i = 0; i < per; i++) {
        binStart[b * (NB_ + 1) + lane * per + i] = acc;
        off[b * NB_ + lane * per + i] = acc;
        acc += cnt[base + i];
    }
    if (lane == 63) binStart[b * (NB_ + 1) + NB_] = acc;
}

// Scatter masked-in pixel records into bin-sorted order.
// Record: [k2*nx, k2*ny, k2*nz, v0, v1, v2, v0^2, v1^2, v2^2, 0,0,0] (48B)
__global__ __launch_bounds__(256) void scatter_kernel(
    const float* __restrict__ img, const float* __restrict__ nm,
    const int* __restrict__ mask, const int* __restrict__ kappa,
    int* __restrict__ off, float* __restrict__ pk)
{
    int idx = blockIdx.x * 256 + threadIdx.x;
    if (idx >= B_ * N_) return;
    if (mask[idx] <= 0) return;
    int b = idx / N_, n = idx - b * N_;
    const float* nb = nm + (size_t)b * 3 * N_ + n;
    float nx = nb[0], ny = nb[N_], nz = nb[2 * N_];
    int bin = pixel_bin(nx, ny, nz);
    int pos = atomicAdd(&off[b * NB_ + bin], 1);
    const float* ib = img + (size_t)b * C_ * N_ + n;
    float v0 = ib[0], v1 = ib[N_], v2 = ib[2 * N_];
    float k2 = (float)kappa[0] * LOG2E;
    float* o = pk + ((size_t)b * N_ + pos) * 12;
    o[0] = k2 * nx; o[1] = k2 * ny; o[2] = k2 * nz;
    o[3] = v0;      o[4] = v1;      o[5] = v2;
    o[6] = v0 * v0; o[7] = v1 * v1; o[8] = v2 * v2;
    o[9] = 0.0f; o[10] = 0.0f; o[11] = 0.0f;
}

// ---------------------------------------------------------------------------
// Main: 1 block (2 waves) per (b, 16x16 direction tile, bin-class s).
// Lane owns 4 c's (identical in both waves); waves split the record stream
// by parity and reduce through LDS at the end. Exact cell-vs-tile-cone
// rejection; accepted bins processed densely with broadcast loads.
// ---------------------------------------------------------------------------
__global__ __launch_bounds__(64 * WPB_) void main_kernel(
    const float* __restrict__ pk, const int* __restrict__ binStart,
    const int* __restrict__ kappa, float* __restrict__ part)
{
    __shared__ float red[64 * 25];     // stride 25: conflict-free reduce

    int bid  = blockIdx.x;
    int s    = bid & (S_ - 1);
    int tile = (bid >> 3) & 255;
    int b    = bid >> 11;
    int tu   = tile & 15, tv = tile >> 4;
    int w    = threadIdx.x >> 6;       // wave id within block
    int lane = threadIdx.x & 63;

    float k  = (float)kappa[0];
    float k2 = k * LOG2E;

    // Directions for this lane's 4 c's within the 16x16 tile
    float Mx[4], My[4], Mz[4];
#pragma unroll
    for (int j = 0; j < 4; j++) {
        int cl = j * 64 + lane;
        int u  = tu * 16 + (cl & 15);
        int v  = tv * 16 + (cl >> 4);
        float p  = 4.0f * ((u + 0.5f) * (1.0f / OS_) - 0.5f);
        float q  = -4.0f * ((v + 0.5f) * (1.0f / OS_) - 0.5f);
        float pp = p * p + q * q;
        float inv = 1.0f / (1.0f + pp);
        Mx[j] = 2.0f * p * inv;
        My[j] = 2.0f * q * inv;
        Mz[j] = (1.0f - pp) * inv;
    }

    // Tile center direction + exact tile cone (min dot over the 256 M's)
    float pc  = 4.0f * ((tu * 16 + 8.0f) * (1.0f / OS_) - 0.5f);
    float qc  = -4.0f * ((tv * 16 + 8.0f) * (1.0f / OS_) - 0.5f);
    float ppc = pc * pc + qc * qc, invc = 1.0f / (1.0f + ppc);
    float Tx = 2.0f * pc * invc, Ty = 2.0f * qc * invc, Tz = (1.0f - ppc) * invc;

    float ctile = 1.0f;
#pragma unroll
    for (int j = 0; j < 4; j++)
        ctile = fminf(ctile, Mx[j] * Tx + My[j] * Ty + Mz[j] * Tz);
#pragma unroll
    for (int o = 32; o; o >>= 1) ctile = fminf(ctile, __shfl_xor(ctile, o));

    float dpthr = 1.0f - TAU_ / k;
    dpthr = fminf(fmaxf(dpthr, -1.0f), 1.0f);
    ctile = fminf(fmaxf(ctile, -1.0f), 1.0f);
    float theta = acosf(dpthr) + acosf(ctile);
    float rhs = (theta >= PI_) ? -2.0f : cosf(theta);   // accept all if cone covers sphere

    float rT   = sqrtf(Tx * Tx + Ty * Ty);
    float phiT = atan2f(Ty, Tx);

    float acc[4][6];
#pragma unroll
    for (int j = 0; j < 4; j++)
#pragma unroll
        for (int i = 0; i < 6; i++) acc[j][i] = 0.0f;

    const int* bs = binStart + b * (NB_ + 1);
    const float4* pkb = (const float4*)(pk + (size_t)b * N_ * 12);

    const int ng = NB_ / (64 * S_);    // 4 ballot rounds
    for (int g = 0; g < ng; g++) {
        // lane tests bin = s + S*(g*64+lane): exact max of n.T over the (z,phi) cell
        int bin = s + S_ * (g * 64 + lane);
        int zi = bin >> 6, fi = bin & (NF_ - 1);
        float z0 = -1.0f + zi * (2.0f / NZ_);
        float z1 = z0 + (2.0f / NZ_);
        float hw  = PI_ / NF_;
        float mid = -PI_ + (2.0f * PI_ / NF_) * fi + hw;
        float d = phiT - mid;
        d = d - (2.0f * PI_) * rintf(d * (0.5f / PI_));
        d = fabsf(d);
        float cmax = (d <= hw) ? 1.0f : cosf(d - hw);
        float A  = rT * cmax;
        float g0 = A * sqrtf(fmaxf(0.0f, 1.0f - z0 * z0)) + Tz * z0;
        float g1 = A * sqrtf(fmaxf(0.0f, 1.0f - z1 * z1)) + Tz * z1;
        float gm = fmaxf(g0, g1);
        if (A > 0.0f) {
            float s2 = A * A + Tz * Tz;
            float zs = Tz * rsqrtf(s2);
            if (zs > z0 && zs < z1) gm = sqrtf(s2);
        }
        unsigned long long mball = __ballot(gm >= rhs);

        while (mball) {
            int l = __builtin_ctzll(mball);
            mball &= mball - 1;
            int bb = s + S_ * (g * 64 + l);
            int st = bs[bb], en = bs[bb + 1];
            const float4* rec = pkb + ((size_t)(st + w)) * 3;
            for (int i = st + w; i < en; i += WPB_, rec += 3 * WPB_) {
                float4 a0 = rec[0];   // k2*nx, k2*ny, k2*nz, v0
                float4 a1 = rec[1];   // v1, v2, v0^2, v1^2
                float4 a2 = rec[2];   // v2^2, pad
#pragma unroll
                for (int j = 0; j < 4; j++) {
                    float arg = fmaf(a0.x, Mx[j], fmaf(a0.y, My[j], fmaf(a0.z, Mz[j], -k2)));
                    float f = __builtin_amdgcn_exp2f(arg);   // exp(-k*(1-dp))
                    acc[j][0] = fmaf(f, a0.w, acc[j][0]);
                    acc[j][1] = fmaf(f, a1.x, acc[j][1]);
                    acc[j][2] = fmaf(f, a1.y, acc[j][2]);
                    acc[j][3] = fmaf(f, a1.z, acc[j][3]);
                    acc[j][4] = fmaf(f, a1.w, acc[j][4]);
                    acc[j][5] = fmaf(f, a2.x, acc[j][5]);
                }
            }
        }
    }

    // Cross-wave reduce through LDS, then wave 0 writes part
    if (w == 1) {
#pragma unroll
        for (int j = 0; j < 4; j++)
#pragma unroll
            for (int i = 0; i < 6; i++) red[lane * 25 + j * 6 + i] = acc[j][i];
    }
    __syncthreads();
    if (w == 0) {
#pragma unroll
        for (int j = 0; j < 4; j++) {
            int cl = j * 64 + lane;
            int u  = tu * 16 + (cl & 15);
            int v  = tv * 16 + (cl >> 4);
            int c  = v * OS_ + u;
            size_t base = (((size_t)b * OUT_ + c) * S_ + s) * 6;
#pragma unroll
            for (int i = 0; i < 6; i++)
                part[base + i] = acc[j][i] + red[lane * 25 + j * 6 + i];
        }
    }
}

// ---------------------------------------------------------------------------
__global__ __launch_bounds__(256) void finalize_kernel(
    const float* __restrict__ part, const int* __restrict__ kappa,
    float* __restrict__ out)
{
    int idx = blockIdx.x * 256 + threadIdx.x;
    if (idx >= B_ * OUT_) return;
    int b = idx / OUT_;
    int c = idx - b * OUT_;

    float k = (float)kappa[0];
    float coef = k / (2.0f * PI_ * (1.0f - expf(-2.0f * k)));

    float s[6] = {0, 0, 0, 0, 0, 0};
    const float* pbase = part + (size_t)idx * S_ * 6;
#pragma unroll
    for (int sp = 0; sp < S_; sp++) {
#pragma unroll
        for (int i = 0; i < 6; i++) s[i] += pbase[sp * 6 + i];
    }
#pragma unroll
    for (int ch = 0; ch < C_; ch++) {
        out[((size_t)(b * C_ + ch)) * OUT_ + c] = (coef * s[3 + ch]) / (coef * s[ch] + 0.001f);
    }
}

// ---------------------------------------------------------------------------
extern "C" void kernel_launch(void* const* d_in, const int* in_sizes, int n_in,
                              void* d_out, int out_size, void* d_ws, size_t ws_size,
                              hipStream_t stream)
{
    const float* img   = (const float*)d_in[0];
    const float* nm    = (const float*)d_in[1];
    const int*   mask  = (const int*)d_in[2];
    const int*   kappa = (const int*)d_in[3];
    float* out = (float*)d_out;

    char*  ws       = (char*)d_ws;
    size_t pk_bytes = (size_t)B_ * N_ * 12 * sizeof(float);
    size_t part_b   = (size_t)B_ * OUT_ * S_ * 6 * sizeof(float);

    float* pk        = (float*)ws;
    float* part      = (float*)(ws + pk_bytes);
    int*   cnt       = (int*)(ws + pk_bytes + part_b);
    int*   off       = cnt + B_ * NB_;
    int*   binStart  = off + B_ * NB_;

    hipMemsetAsync(cnt, 0, (size_t)B_ * NB_ * sizeof(int), stream);
    hipLaunchKernelGGL(hist_kernel, dim3((B_ * N_ + 255) / 256), dim3(256), 0, stream,
                       nm, mask, cnt);
    hipLaunchKernelGGL(scan_kernel, dim3(B_), dim3(64), 0, stream,
                       cnt, binStart, off);
    hipLaunchKernelGGL(scatter_kernel, dim3((B_ * N_ + 255) / 256), dim3(256), 0, stream,
                       img, nm, mask, kappa, off, pk);
    hipLaunchKernelGGL(main_kernel, dim3(B_ * 256 * S_), dim3(64 * WPB_), 0, stream,
                       pk, binStart, kappa, part);
    hipLaunchKernelGGL(finalize_kernel, dim3((B_ * OUT_ + 255) / 256), dim3(256), 0, stream,
                       part, kappa, out);
}

// Round 4
// 118.396 us; speedup vs baseline: 4.2977x; 1.0837x over previous
//
#include <hip/hip_runtime.h>
#include <math.h>

// Problem-instance constants (B=2, C=3, H=W=128, out_size=256, kappa=100)
#define B_    2
#define C_    3
#define N_    16384    // H*W
#define OS_   256
#define OUT_  65536    // OS*OS
#define NZ_   32       // z-bands
#define NF_   64       // azimuth sectors (= wave width)
#define NB_   2048     // NZ_*NF_ spherical bins
#define S_    4        // range-split classes across blocks
#define WPB_  4        // waves per block (further contiguous split)
#define TAU_  27.0f    // skip cells where k*(1-dp) > TAU for the whole (tile,cell)
#define LOG2E 1.44269504088896340736f
#define PI_   3.14159265358979323846f

typedef float v2f __attribute__((ext_vector_type(2)));
#define PK_FMA(a,b,c) __builtin_elementwise_fma(a,b,c)

// ---------------------------------------------------------------------------
__device__ __forceinline__ int pixel_bin(float nx, float ny, float nz) {
    int zi = (int)((nz + 1.0f) * (NZ_ * 0.5f));
    zi = min(max(zi, 0), NZ_ - 1);
    float phi = atan2f(ny, nx);                       // [-pi, pi]
    int fi = (int)((phi + PI_) * (NF_ / (2.0f * PI_)));
    fi = min(max(fi, 0), NF_ - 1);
    return zi * NF_ + fi;
}

// Histogram of masked-in pixels over bins
__global__ __launch_bounds__(256) void hist_kernel(
    const float* __restrict__ nm, const int* __restrict__ mask, int* __restrict__ cnt)
{
    int idx = blockIdx.x * 256 + threadIdx.x;
    if (idx >= B_ * N_) return;
    if (mask[idx] <= 0) return;
    int b = idx / N_, n = idx - b * N_;
    const float* nb = nm + (size_t)b * 3 * N_ + n;
    int bin = pixel_bin(nb[0], nb[N_], nb[2 * N_]);
    atomicAdd(&cnt[b * NB_ + bin], 1);
}

// Wave-parallel exclusive scan over NB_ bins; one 64-lane wave per b.
__global__ __launch_bounds__(64) void scan_kernel(
    const int* __restrict__ cnt, int* __restrict__ binStart, int* __restrict__ off)
{
    int b = blockIdx.x;
    int lane = threadIdx.x;
    const int per = NB_ / 64;          // 32 bins per lane
    int base = b * NB_ + lane * per;

    int sum = 0;
#pragma unroll
    for (int i = 0; i < per; i++) sum += cnt[base + i];

    int inc = sum;                      // inclusive scan across lanes
#pragma unroll
    for (int o = 1; o < 64; o <<= 1) {
        int t = __shfl_up(inc, o);
        if (lane >= o) inc += t;
    }
    int acc = inc - sum;                // exclusive prefix for this lane's chunk

#pragma unroll
    for (int i = 0; i < per; i++) {
        binStart[b * (NB_ + 1) + lane * per + i] = acc;
        off[b * NB_ + lane * per + i] = acc;
        acc += cnt[base + i];
    }
    if (lane == 63) binStart[b * (NB_ + 1) + NB_] = acc;
}

// Scatter masked-in pixel records into bin-sorted order.
// Record: [k2*nx, k2*ny, k2*nz, v0, v1, v2, v0^2, v1^2, v2^2, 0,0,0] (48B)
__global__ __launch_bounds__(256) void scatter_kernel(
    const float* __restrict__ img, const float* __restrict__ nm,
    const int* __restrict__ mask, const int* __restrict__ kappa,
    int* __restrict__ off, float* __restrict__ pk)
{
    int idx = blockIdx.x * 256 + threadIdx.x;
    if (idx >= B_ * N_) return;
    if (mask[idx] <= 0) return;
    int b = idx / N_, n = idx - b * N_;
    const float* nb = nm + (size_t)b * 3 * N_ + n;
    float nx = nb[0], ny = nb[N_], nz = nb[2 * N_];
    int bin = pixel_bin(nx, ny, nz);
    int pos = atomicAdd(&off[b * NB_ + bin], 1);
    const float* ib = img + (size_t)b * C_ * N_ + n;
    float v0 = ib[0], v1 = ib[N_], v2 = ib[2 * N_];
    float k2 = (float)kappa[0] * LOG2E;
    float* o = pk + ((size_t)b * N_ + pos) * 12;
    o[0] = k2 * nx; o[1] = k2 * ny; o[2] = k2 * nz;
    o[3] = v0;      o[4] = v1;      o[5] = v2;
    o[6] = v0 * v0; o[7] = v1 * v1; o[8] = v2 * v2;
    o[9] = 0.0f; o[10] = 0.0f; o[11] = 0.0f;
}

// ---------------------------------------------------------------------------
// Plan: one wave per (b, tile). For each z-band, all 64 lanes test their
// azimuth cell against the widened tile cone; accepted sectors form a
// contiguous arc -> emit up to 2 contiguous record ranges per band.
// ---------------------------------------------------------------------------
__global__ __launch_bounds__(64) void plan_kernel(
    const int* __restrict__ binStart, const int* __restrict__ kappa,
    int* __restrict__ plan)
{
    int bt = blockIdx.x;               // b*256 + tile
    int b = bt >> 8, tile = bt & 255;
    int tu = tile & 15, tv = tile >> 4;
    int lane = threadIdx.x;
    float k = (float)kappa[0];

    // Tile center direction
    float pc  = 4.0f * ((tu * 16 + 8.0f) * (1.0f / OS_) - 0.5f);
    float qc  = -4.0f * ((tv * 16 + 8.0f) * (1.0f / OS_) - 0.5f);
    float ppc = pc * pc + qc * qc, invc = 1.0f / (1.0f + ppc);
    float Tx = 2.0f * pc * invc, Ty = 2.0f * qc * invc, Tz = (1.0f - ppc) * invc;

    // Exact tile cone: min dot over the 256 M's
    float ctile = 1.0f;
#pragma unroll
    for (int j = 0; j < 4; j++) {
        int cl = j * 64 + lane;
        int u = tu * 16 + (cl & 15), v = tv * 16 + (cl >> 4);
        float p = 4.0f * ((u + 0.5f) * (1.0f / OS_) - 0.5f);
        float q = -4.0f * ((v + 0.5f) * (1.0f / OS_) - 0.5f);
        float pp = p * p + q * q;
        float inv = 1.0f / (1.0f + pp);
        float mx = 2.0f * p * inv, my = 2.0f * q * inv, mz = (1.0f - pp) * inv;
        ctile = fminf(ctile, mx * Tx + my * Ty + mz * Tz);
    }
#pragma unroll
    for (int o = 32; o; o >>= 1) ctile = fminf(ctile, __shfl_xor(ctile, o));

    float dpthr = fminf(fmaxf(1.0f - TAU_ / k, -1.0f), 1.0f);
    ctile = fminf(fmaxf(ctile, -1.0f), 1.0f);
    float theta = acosf(dpthr) + acosf(ctile);
    float rhs = (theta >= PI_) ? -2.0f : cosf(theta);

    float rT   = sqrtf(Tx * Tx + Ty * Ty);
    float phiT = atan2f(Ty, Tx);
    int fiT = min(max((int)((phiT + PI_) * (NF_ / (2.0f * PI_))), 0), NF_ - 1);

    const int* bs = binStart + b * (NB_ + 1);

    for (int zi = 0; zi < NZ_; zi++) {
        // cell (zi, fi=lane): exact max of n.T over the cell
        float z0 = -1.0f + zi * (2.0f / NZ_);
        float z1 = z0 + (2.0f / NZ_);
        float hw  = PI_ / NF_;
        float mid = -PI_ + (2.0f * PI_ / NF_) * lane + hw;
        float d = phiT - mid;
        d = d - (2.0f * PI_) * rintf(d * (0.5f / PI_));
        d = fabsf(d);
        float cmax = (d <= hw) ? 1.0f : cosf(d - hw);
        float A  = rT * cmax;
        float g0 = A * sqrtf(fmaxf(0.0f, 1.0f - z0 * z0)) + Tz * z0;
        float g1 = A * sqrtf(fmaxf(0.0f, 1.0f - z1 * z1)) + Tz * z1;
        float gm = fmaxf(g0, g1);
        if (A > 0.0f) {
            float s2 = A * A + Tz * Tz;
            float zs = Tz * rsqrtf(s2);
            if (zs > z0 && zs < z1) gm = sqrtf(s2);
        }
        unsigned long long m = __ballot(gm >= rhs);

        int base = zi * NF_;
        int st0 = 0, en0 = 0, st1 = 0, en1 = 0;
        if (m) {
            bool full = (~m == 0ull) || !((m >> fiT) & 1ull);  // fallback: superset
            if (!full) {
                unsigned long long r = fiT ? ((m >> fiT) | (m << (64 - fiT))) : m;
                unsigned long long nr = ~r;                    // != 0 here
                int bcnt = __builtin_ctzll(nr);                // >= 1
                int acnt = __builtin_clzll(nr);
                if (bcnt + acnt >= NF_) full = true;
                else {
                    int lo = fiT - acnt, hi = fiT + bcnt - 1;
                    if (lo >= 0 && hi < NF_) {
                        st0 = bs[base + lo]; en0 = bs[base + hi + 1];
                    } else if (lo < 0) {       // arc = [lo+64,63] U [0,hi]
                        st0 = bs[base];            en0 = bs[base + hi + 1];
                        st1 = bs[base + lo + NF_]; en1 = bs[base + NF_];
                    } else {                   // hi >= 64: arc = [lo,63] U [0,hi-64]
                        st0 = bs[base];       en0 = bs[base + hi - NF_ + 1];
                        st1 = bs[base + lo];  en1 = bs[base + NF_];
                    }
                }
            }
            if (full) { st0 = bs[base]; en0 = bs[base + NF_]; }
        }
        if (lane == 0) {
            int* o = plan + ((size_t)bt * NZ_ + zi) * 4;
            o[0] = st0; o[1] = en0; o[2] = st1; o[3] = en1;
        }
    }
}

// ---------------------------------------------------------------------------
// Main: 1 block (4 waves) per (b, tile, s). Lane owns 4 c's packed as 2 v2f
// pairs (v_pk_fma_f32). Piece p = s*WPB+w takes an exact contiguous 1/16 of
// every accepted range -> long streaming loops, loads pipeline.
// ---------------------------------------------------------------------------
__global__ __launch_bounds__(64 * WPB_, 6) void main_kernel(
    const float* __restrict__ pk, const int* __restrict__ plan,
    const int* __restrict__ kappa, float* __restrict__ part)
{
    __shared__ int   sPlan[NZ_ * 4];
    __shared__ float red[64 * 25];     // stride 25: conflict-free reduce

    int bid  = blockIdx.x;
    int s    = bid & (S_ - 1);
    int bt   = bid >> 2;               // b*256 + tile
    int tile = bt & 255;
    int b    = bt >> 8;
    int tu   = tile & 15, tv = tile >> 4;
    int tid  = threadIdx.x;
    int w    = tid >> 6, lane = tid & 63;

    if (tid < NZ_ * 4) sPlan[tid] = plan[(size_t)bt * (NZ_ * 4) + tid];
    __syncthreads();

    float k  = (float)kappa[0];
    float k2 = k * LOG2E;
    v2f  mk2 = {-k2, -k2};

    // Directions for this lane's 4 c's, packed (j0,j1) and (j2,j3)
    float mxv[4], myv[4], mzv[4];
#pragma unroll
    for (int j = 0; j < 4; j++) {
        int cl = j * 64 + lane;
        int u  = tu * 16 + (cl & 15);
        int v  = tv * 16 + (cl >> 4);
        float p  = 4.0f * ((u + 0.5f) * (1.0f / OS_) - 0.5f);
        float q  = -4.0f * ((v + 0.5f) * (1.0f / OS_) - 0.5f);
        float pp = p * p + q * q;
        float inv = 1.0f / (1.0f + pp);
        mxv[j] = 2.0f * p * inv;
        myv[j] = 2.0f * q * inv;
        mzv[j] = (1.0f - pp) * inv;
    }
    v2f Mx01 = {mxv[0], mxv[1]}, My01 = {myv[0], myv[1]}, Mz01 = {mzv[0], mzv[1]};
    v2f Mx23 = {mxv[2], mxv[3]}, My23 = {myv[2], myv[3]}, Mz23 = {mzv[2], mzv[3]};

    v2f a0c[6], a1c[6];
#pragma unroll
    for (int i = 0; i < 6; i++) { a0c[i] = (v2f){0.0f, 0.0f}; a1c[i] = (v2f){0.0f, 0.0f}; }

    const float4* pkb = (const float4*)(pk + (size_t)b * N_ * 12);
    int p = s * WPB_ + w;              // 0..15

    for (int zi = 0; zi < NZ_; zi++) {
        int st0 = sPlan[zi * 4 + 0], en0 = sPlan[zi * 4 + 1];
        int st1 = sPlan[zi * 4 + 2], en1 = sPlan[zi * 4 + 3];
#pragma unroll
        for (int rr = 0; rr < 2; rr++) {
            int st = rr ? st1 : st0;
            int en = rr ? en1 : en0;
            int len = en - st;
            if (len <= 0) continue;
            int ia = st + ((len * p) >> 4);
            int ie = st + ((len * (p + 1)) >> 4);
            const float4* rec = pkb + (size_t)ia * 3;
            for (int i = ia; i < ie; i++, rec += 3) {
                float4 r0 = rec[0];    // k2*nx, k2*ny, k2*nz, v0
                float4 r1 = rec[1];    // v1, v2, v0^2, v1^2
                float4 r2 = rec[2];    // v2^2, pad
                v2f nX = {r0.x, r0.x}, nY = {r0.y, r0.y}, nZ = {r0.z, r0.z};
                v2f g01 = PK_FMA(nX, Mx01, PK_FMA(nY, My01, PK_FMA(nZ, Mz01, mk2)));
                v2f g23 = PK_FMA(nX, Mx23, PK_FMA(nY, My23, PK_FMA(nZ, Mz23, mk2)));
                v2f f01 = {__builtin_amdgcn_exp2f(g01.x), __builtin_amdgcn_exp2f(g01.y)};
                v2f f23 = {__builtin_amdgcn_exp2f(g23.x), __builtin_amdgcn_exp2f(g23.y)};
                v2f t;
                t = (v2f){r0.w, r0.w}; a0c[0] = PK_FMA(f01, t, a0c[0]); a1c[0] = PK_FMA(f23, t, a1c[0]);
                t = (v2f){r1.x, r1.x}; a0c[1] = PK_FMA(f01, t, a0c[1]); a1c[1] = PK_FMA(f23, t, a1c[1]);
                t = (v2f){r1.y, r1.y}; a0c[2] = PK_FMA(f01, t, a0c[2]); a1c[2] = PK_FMA(f23, t, a1c[2]);
                t = (v2f){r1.z, r1.z}; a0c[3] = PK_FMA(f01, t, a0c[3]); a1c[3] = PK_FMA(f23, t, a1c[3]);
                t = (v2f){r1.w, r1.w}; a0c[4] = PK_FMA(f01, t, a0c[4]); a1c[4] = PK_FMA(f23, t, a1c[4]);
                t = (v2f){r2.x, r2.x}; a0c[5] = PK_FMA(f01, t, a0c[5]); a1c[5] = PK_FMA(f23, t, a1c[5]);
            }
        }
    }

    // Unpack to per-j scalars
    float accf[4][6];
#pragma unroll
    for (int i = 0; i < 6; i++) {
        accf[0][i] = a0c[i].x; accf[1][i] = a0c[i].y;
        accf[2][i] = a1c[i].x; accf[3][i] = a1c[i].y;
    }

    // Cross-wave reduce through LDS (sequential adds), wave 0 writes part
    if (w == 1) {
#pragma unroll
        for (int j = 0; j < 4; j++)
#pragma unroll
            for (int i = 0; i < 6; i++) red[lane * 25 + j * 6 + i] = accf[j][i];
    }
    __syncthreads();
    if (w == 2) {
#pragma unroll
        for (int j = 0; j < 4; j++)
#pragma unroll
            for (int i = 0; i < 6; i++) red[lane * 25 + j * 6 + i] += accf[j][i];
    }
    __syncthreads();
    if (w == 3) {
#pragma unroll
        for (int j = 0; j < 4; j++)
#pragma unroll
            for (int i = 0; i < 6; i++) red[lane * 25 + j * 6 + i] += accf[j][i];
    }
    __syncthreads();
    if (w == 0) {
#pragma unroll
        for (int j = 0; j < 4; j++) {
            int cl = j * 64 + lane;
            int u  = tu * 16 + (cl & 15);
            int v  = tv * 16 + (cl >> 4);
            int c  = v * OS_ + u;
            size_t base = (((size_t)b * OUT_ + c) * S_ + s) * 6;
#pragma unroll
            for (int i = 0; i < 6; i++)
                part[base + i] = accf[j][i] + red[lane * 25 + j * 6 + i];
        }
    }
}

// ---------------------------------------------------------------------------
__global__ __launch_bounds__(256) void finalize_kernel(
    const float* __restrict__ part, const int* __restrict__ kappa,
    float* __restrict__ out)
{
    int idx = blockIdx.x * 256 + threadIdx.x;
    if (idx >= B_ * OUT_) return;
    int b = idx / OUT_;
    int c = idx - b * OUT_;

    float k = (float)kappa[0];
    float coef = k / (2.0f * PI_ * (1.0f - expf(-2.0f * k)));

    float s[6] = {0, 0, 0, 0, 0, 0};
    const float* pbase = part + (size_t)idx * S_ * 6;
#pragma unroll
    for (int sp = 0; sp < S_; sp++) {
#pragma unroll
        for (int i = 0; i < 6; i++) s[i] += pbase[sp * 6 + i];
    }
#pragma unroll
    for (int ch = 0; ch < C_; ch++) {
        out[((size_t)(b * C_ + ch)) * OUT_ + c] = (coef * s[3 + ch]) / (coef * s[ch] + 0.001f);
    }
}

// ---------------------------------------------------------------------------
extern "C" void kernel_launch(void* const* d_in, const int* in_sizes, int n_in,
                              void* d_out, int out_size, void* d_ws, size_t ws_size,
                              hipStream_t stream)
{
    const float* img   = (const float*)d_in[0];
    const float* nm    = (const float*)d_in[1];
    const int*   mask  = (const int*)d_in[2];
    const int*   kappa = (const int*)d_in[3];
    float* out = (float*)d_out;

    char*  ws       = (char*)d_ws;
    size_t pk_bytes = (size_t)B_ * N_ * 12 * sizeof(float);
    size_t part_b   = (size_t)B_ * OUT_ * S_ * 6 * sizeof(float);

    float* pk        = (float*)ws;
    float* part      = (float*)(ws + pk_bytes);
    int*   cnt       = (int*)(ws + pk_bytes + part_b);
    int*   off       = cnt + B_ * NB_;
    int*   binStart  = off + B_ * NB_;
    int*   plan      = binStart + B_ * (NB_ + 1);

    hipMemsetAsync(cnt, 0, (size_t)B_ * NB_ * sizeof(int), stream);
    hipLaunchKernelGGL(hist_kernel, dim3((B_ * N_ + 255) / 256), dim3(256), 0, stream,
                       nm, mask, cnt);
    hipLaunchKernelGGL(scan_kernel, dim3(B_), dim3(64), 0, stream,
                       cnt, binStart, off);
    hipLaunchKernelGGL(scatter_kernel, dim3((B_ * N_ + 255) / 256), dim3(256), 0, stream,
                       img, nm, mask, kappa, off, pk);
    hipLaunchKernelGGL(plan_kernel, dim3(B_ * 256), dim3(64), 0, stream,
                       binStart, kappa, plan);
    hipLaunchKernelGGL(main_kernel, dim3(B_ * 256 * S_), dim3(64 * WPB_), 0, stream,
                       pk, plan, kappa, part);
    hipLaunchKernelGGL(finalize_kernel, dim3((B_ * OUT_ + 255) / 256), dim3(256), 0, stream,
                       part, kappa, out);
}